// Round 15
// baseline (228.162 us; speedup 1.0000x reference)
//
#include <hip/hip_runtime.h>
#include <hip/hip_bf16.h>

#define F      128
#define NROWS  2048
#define MROWS  2048
#define MT     32          // m-tiles of 64
#define LOG2E  1.44269504088896340736f

typedef float f32x4 __attribute__((ext_vector_type(4)));

// --- Kernel 1: projections + ELU/w2 precompute + w2sum ----------------------
// a = (embeds@W1)[n][g], b = (base@W1)[m][g], w = w2[g]
// PA row-chunk layout: PA[row][ch*16 + 0..7]=p0=(a+1)w, [8..15]=p1=exp(a)w
// BT4 transposed B layout: BT4[(ch*4+q)][m][e], f=q*4+e:
//   f 0..7 = p0=-b*w (g=ch*8+f), f 8..15 = p1=exp(-b) (g=ch*8+f-8)
// w*elu(a-b) + w = med3(p0A + p0B, p1A * p1B, w)
__global__ __launch_bounds__(256) void proj_kernel(
    const float* __restrict__ embeds, const float* __restrict__ base,
    const float* __restrict__ W1, const float* __restrict__ w2,
    float* __restrict__ PA, float* __restrict__ BT4,
    float* __restrict__ w2sum)
{
    const int tid = threadIdx.x;
    const int sub = tid >> 7;
    const int g   = tid & 127;
    const int row = blockIdx.x * 2 + sub;

    __shared__ float xs[2][F];
    {
        const float* src = (row < NROWS) ? &embeds[(size_t)row * F]
                                         : &base[(size_t)(row - NROWS) * F];
        xs[sub][g] = src[g];
    }
    __syncthreads();

    float acc = 0.0f;
#pragma unroll 8
    for (int f = 0; f < F; ++f)
        acc = fmaf(xs[sub][f], W1[f * F + g], acc);

    const float wv = w2[g];
    const int   ch = g >> 3, o = g & 7;
    if (row < NROWS) {
        float* dst = PA + (size_t)row * 256 + ch * 16 + o;
        dst[0] = (acc + 1.0f) * wv;
        dst[8] = __builtin_amdgcn_exp2f(acc * LOG2E) * wv;
    } else {
        const int m  = row - NROWS;
        const int f0 = o, f1 = 8 + o;
        BT4[((size_t)(ch * 4 + (f0 >> 2)) * 2048 + m) * 4 + (f0 & 3)] = -acc * wv;
        BT4[((size_t)(ch * 4 + (f1 >> 2)) * 2048 + m) * 4 + (f1 & 3)] =
            __builtin_amdgcn_exp2f(-acc * LOG2E);
    }

    if (blockIdx.x == 0 && tid < 64) {
        float s = w2[tid] + w2[tid + 64];
#pragma unroll
        for (int k = 1; k < 64; k <<= 1) s += __shfl_xor(s, k);
        if (tid == 0) *w2sum = s;
    }
}

// --- Kernel 2: pair kernel -----------------------------------------------------
// grid (64,32), 256 threads = 4 waves; wave = 8 n-rows x 64 m (lane = m).
// ZERO LDS, ZERO barriers. A loaded per-lane (uniform addr -> L1 broadcast),
// ping-pong aA/aB across rows; B per-lane coalesced from BT4, ping-pong bA/bB
// across chunks (loop unrolled x2). All buffers statically indexed.
__global__ __launch_bounds__(256, 4) void pair_kernel(
    const float* __restrict__ PA, const float* __restrict__ BT4,
    const float* __restrict__ w2, const float* __restrict__ w2sum_p,
    const float* __restrict__ brew, float* __restrict__ partials)
{
    const int lane = threadIdx.x & 63;
    const int wv   = threadIdx.x >> 6;
    const int nt   = blockIdx.x, mt = blockIdx.y;
    const int n0   = nt * 32 + wv * 8;
    const int m0   = mt * 64;

    const float* bcol = BT4 + (size_t)(m0 + lane) * 4;   // per-lane B column
    const float* abase = PA + (size_t)n0 * 256;

    f32x4 aA[4], aB[4], bA[4], bB[4];
    float acc[8];
#pragma unroll
    for (int r = 0; r < 8; ++r) acc[r] = 0.0f;

#define LOADB(DST, CH) {                                                       \
    const int c_ = (CH);                                                       \
    DST[0] = *(const f32x4*)&bcol[(size_t)(c_ * 4 + 0) * 8192];                \
    DST[1] = *(const f32x4*)&bcol[(size_t)(c_ * 4 + 1) * 8192];                \
    DST[2] = *(const f32x4*)&bcol[(size_t)(c_ * 4 + 2) * 8192];                \
    DST[3] = *(const f32x4*)&bcol[(size_t)(c_ * 4 + 3) * 8192]; }

#define LOADA(DST, CH, R) {                                                    \
    const float* ap_ = abase + (size_t)(R) * 256 + (CH) * 16;                  \
    DST[0] = *(const f32x4*)&ap_[0];                                           \
    DST[1] = *(const f32x4*)&ap_[4];                                           \
    DST[2] = *(const f32x4*)&ap_[8];                                           \
    DST[3] = *(const f32x4*)&ap_[12]; }

#define COMPUTE(R, A_, B_)                                                     \
    {                                                                          \
        const float s0 = __builtin_amdgcn_fmed3f(A_[0][0] + B_[0][0], A_[2][0] * B_[2][0], w0); \
        const float s1 = __builtin_amdgcn_fmed3f(A_[0][1] + B_[0][1], A_[2][1] * B_[2][1], w1); \
        const float s2 = __builtin_amdgcn_fmed3f(A_[0][2] + B_[0][2], A_[2][2] * B_[2][2], w2_); \
        const float s3 = __builtin_amdgcn_fmed3f(A_[0][3] + B_[0][3], A_[2][3] * B_[2][3], w3); \
        const float s4 = __builtin_amdgcn_fmed3f(A_[1][0] + B_[1][0], A_[3][0] * B_[3][0], w4); \
        const float s5 = __builtin_amdgcn_fmed3f(A_[1][1] + B_[1][1], A_[3][1] * B_[3][1], w5); \
        const float s6 = __builtin_amdgcn_fmed3f(A_[1][2] + B_[1][2], A_[3][2] * B_[3][2], w6); \
        const float s7 = __builtin_amdgcn_fmed3f(A_[1][3] + B_[1][3], A_[3][3] * B_[3][3], w7); \
        acc[R] += ((s0 + s1) + (s2 + s3)) + ((s4 + s5) + (s6 + s7));           \
    }

// one chunk: prefetch B for next chunk, stream 8 rows with aA/aB ping-pong.
// invariant: on entry aA holds (CH, row0); on exit aA holds (CHN, row0).
#define CHUNK(CH, BCUR, BNXT) {                                                \
    const int chn_ = ((CH) + 1 < 16) ? (CH) + 1 : 15;                          \
    LOADB(BNXT, chn_)                                                          \
    const float* w2c_ = w2 + (CH) * 8;                                         \
    const float w0 = w2c_[0], w1 = w2c_[1], w2_ = w2c_[2], w3 = w2c_[3];       \
    const float w4 = w2c_[4], w5 = w2c_[5], w6 = w2c_[6], w7 = w2c_[7];        \
    LOADA(aB, (CH), 1) COMPUTE(0, aA, BCUR)                                    \
    LOADA(aA, (CH), 2) COMPUTE(1, aB, BCUR)                                    \
    LOADA(aB, (CH), 3) COMPUTE(2, aA, BCUR)                                    \
    LOADA(aA, (CH), 4) COMPUTE(3, aB, BCUR)                                    \
    LOADA(aB, (CH), 5) COMPUTE(4, aA, BCUR)                                    \
    LOADA(aA, (CH), 6) COMPUTE(5, aB, BCUR)                                    \
    LOADA(aB, (CH), 7) COMPUTE(6, aA, BCUR)                                    \
    LOADA(aA, chn_, 0) COMPUTE(7, aB, BCUR)                                    \
    }

    LOADB(bA, 0)
    LOADA(aA, 0, 0)
#pragma unroll 1
    for (int ch = 0; ch < 16; ch += 2) {
        CHUNK(ch,     bA, bB)
        CHUNK(ch + 1, bB, bA)
    }
#undef CHUNK
#undef COMPUTE
#undef LOADA
#undef LOADB

    // --- epilogue: per-row inverse-distance, reduce over 64 m-lanes -------------
    const float w2sum = *w2sum_p;
    const float rv    = brew[m0 + lane];

#pragma unroll
    for (int r = 0; r < 8; ++r) {
        const float dist = fabsf(acc[r] - w2sum);
        const float wgt  = 1.0f / (dist + 1e-4f);
        float sw  = wgt;
        float swr = wgt * rv;
#pragma unroll
        for (int k = 1; k < 64; k <<= 1) {
            sw  += __shfl_xor(sw, k);
            swr += __shfl_xor(swr, k);
        }
        if (lane == 0) {
            const int n = n0 + r;
            partials[((size_t)n * MT + mt) * 2 + 0] = sw;
            partials[((size_t)n * MT + mt) * 2 + 1] = swr;
        }
    }
}

// --- Kernel 3: reduce tile partials, divide ------------------------------------
__global__ __launch_bounds__(256) void finalize_kernel(
    const float* __restrict__ partials, float* __restrict__ out)
{
    const int n = blockIdx.x * 256 + threadIdx.x;
    if (n < NROWS) {
        float sw = 0.0f, swr = 0.0f;
#pragma unroll
        for (int t = 0; t < MT; ++t) {
            sw  += partials[((size_t)n * MT + t) * 2 + 0];
            swr += partials[((size_t)n * MT + t) * 2 + 1];
        }
        out[n] = swr / sw;
    }
}

extern "C" void kernel_launch(void* const* d_in, const int* in_sizes, int n_in,
                              void* d_out, int out_size, void* d_ws, size_t ws_size,
                              hipStream_t stream)
{
    const float* embeds       = (const float*)d_in[0];  // [2048,128]
    const float* base_embeds  = (const float*)d_in[1];  // [2048,128]
    const float* base_rewards = (const float*)d_in[2];  // [2048]
    const float* W1           = (const float*)d_in[3];  // [128,128] (in,out)
    const float* w2           = (const float*)d_in[4];  // [128,1]
    float* out = (float*)d_out;

    // ws: partials [2048*MT*2] | PA [2048*256] | BT4 [64*2048*4] | w2sum[1]
    float* partials = (float*)d_ws;
    float* PA  = partials + (size_t)NROWS * MT * 2;
    float* BT4 = PA + (size_t)NROWS * 256;
    float* w2s = BT4 + (size_t)64 * 2048 * 4;

    proj_kernel<<<(NROWS + MROWS) / 2, 256, 0, stream>>>(
        embeds, base_embeds, W1, w2, PA, BT4, w2s);

    dim3 grid2(NROWS / 32, MROWS / 64);
    pair_kernel<<<grid2, 256, 0, stream>>>(PA, BT4, w2, w2s, base_rewards, partials);

    finalize_kernel<<<(NROWS + 255) / 256, 256, 0, stream>>>(partials, out);
}

// Round 16
// 102.696 us; speedup vs baseline: 2.2217x; 2.2217x over previous
//
#include <hip/hip_runtime.h>
#include <hip/hip_bf16.h>

#define F      128
#define NROWS  2048
#define MROWS  2048
#define MT     32          // m-tiles of 64
#define LOG2E  1.44269504088896340736f

typedef float f32x4 __attribute__((ext_vector_type(4)));

// --- Kernel 1: projections + ELU/w2 precompute + w2sum ----------------------
// a = (embeds@W1)[n][g], b = (base@W1)[m][g], w = w2[g]
// PA row-chunk layout: PA[row][ch*16 + 0..7]=p0=(a+1)w, [8..15]=p1=exp(a)w
// BT4 transposed B layout: BT4[(ch*4+q)][m][e], f=q*4+e:
//   f 0..7 = p0=-b*w (g=ch*8+f), f 8..15 = p1=exp(-b) (g=ch*8+f-8)
// w*elu(a-b) + w = med3(p0A + p0B, p1A * p1B, w)
__global__ __launch_bounds__(256) void proj_kernel(
    const float* __restrict__ embeds, const float* __restrict__ base,
    const float* __restrict__ W1, const float* __restrict__ w2,
    float* __restrict__ PA, float* __restrict__ BT4,
    float* __restrict__ w2sum)
{
    const int tid = threadIdx.x;
    const int sub = tid >> 7;
    const int g   = tid & 127;
    const int row = blockIdx.x * 2 + sub;

    __shared__ float xs[2][F];
    {
        const float* src = (row < NROWS) ? &embeds[(size_t)row * F]
                                         : &base[(size_t)(row - NROWS) * F];
        xs[sub][g] = src[g];
    }
    __syncthreads();

    float acc = 0.0f;
#pragma unroll 8
    for (int f = 0; f < F; ++f)
        acc = fmaf(xs[sub][f], W1[f * F + g], acc);

    const float wv = w2[g];
    const int   ch = g >> 3, o = g & 7;
    if (row < NROWS) {
        float* dst = PA + (size_t)row * 256 + ch * 16 + o;
        dst[0] = (acc + 1.0f) * wv;
        dst[8] = __builtin_amdgcn_exp2f(acc * LOG2E) * wv;
    } else {
        const int m  = row - NROWS;
        const int f0 = o, f1 = 8 + o;
        BT4[((size_t)(ch * 4 + (f0 >> 2)) * 2048 + m) * 4 + (f0 & 3)] = -acc * wv;
        BT4[((size_t)(ch * 4 + (f1 >> 2)) * 2048 + m) * 4 + (f1 & 3)] =
            __builtin_amdgcn_exp2f(-acc * LOG2E);
    }

    if (blockIdx.x == 0 && tid < 64) {
        float s = w2[tid] + w2[tid + 64];
#pragma unroll
        for (int k = 1; k < 64; k <<= 1) s += __shfl_xor(s, k);
        if (tid == 0) *w2sum = s;
    }
}

// --- Kernel 2: pair kernel -----------------------------------------------------
// grid (64,32), 256 threads = 4 waves; wave = 8 n-rows x 64 m (lane = m).
// ZERO LDS, ZERO barriers. A is wave-uniform -> SGPRs via s_load (readfirstlane
// makes n0 provably uniform); each VALU op uses its 1 allowed SGPR operand:
// v_add(s,v), v_mul(s,v), v_med3(v,v,s). B per-lane coalesced from BT4,
// double-buffered in VGPRs (live set ~50 VGPR -> no spill, no sinking).
__global__ __launch_bounds__(256) void pair_kernel(
    const float* __restrict__ PA, const float* __restrict__ BT4,
    const float* __restrict__ w2, const float* __restrict__ w2sum_p,
    const float* __restrict__ brew, float* __restrict__ partials)
{
    const int lane = threadIdx.x & 63;
    const int wv   = __builtin_amdgcn_readfirstlane(threadIdx.x >> 6);
    const int nt   = blockIdx.x, mt = blockIdx.y;
    const int n0   = nt * 32 + wv * 8;     // uniform
    const int m0   = mt * 64;

    const float* arow = PA + (size_t)n0 * 256;            // uniform -> s_load
    const float* bcol = BT4 + (size_t)(m0 + lane) * 4;    // per-lane

    float acc[8];
#pragma unroll
    for (int r = 0; r < 8; ++r) acc[r] = 0.0f;

    f32x4 bA[4], bB[4];

#define LOADB(DST, CH) {                                                       \
    DST[0] = *(const f32x4*)&bcol[(size_t)((CH) * 4 + 0) * 8192];              \
    DST[1] = *(const f32x4*)&bcol[(size_t)((CH) * 4 + 1) * 8192];              \
    DST[2] = *(const f32x4*)&bcol[(size_t)((CH) * 4 + 2) * 8192];              \
    DST[3] = *(const f32x4*)&bcol[(size_t)((CH) * 4 + 3) * 8192]; }

// one chunk: prefetch next-B into BNXT, then 8 rows of scalar-A x vector-B math
#define CHUNK(CH, BCUR, BNXT) {                                                \
    if ((CH) + 1 < 16) LOADB(BNXT, (CH) + 1)                                   \
    const float* w2c = w2 + (CH) * 8;      /* uniform -> s_load */             \
    const float w0 = w2c[0], w1 = w2c[1], w2_ = w2c[2], w3 = w2c[3];           \
    const float w4 = w2c[4], w5 = w2c[5], w6 = w2c[6], w7 = w2c[7];            \
    _Pragma("unroll")                                                          \
    for (int r = 0; r < 8; ++r) {                                              \
        const float* ap = arow + r * 256 + (CH) * 16;  /* uniform -> s_load */ \
        const float s0 = __builtin_amdgcn_fmed3f(ap[0] + BCUR[0][0], ap[ 8] * BCUR[2][0], w0); \
        const float s1 = __builtin_amdgcn_fmed3f(ap[1] + BCUR[0][1], ap[ 9] * BCUR[2][1], w1); \
        const float s2 = __builtin_amdgcn_fmed3f(ap[2] + BCUR[0][2], ap[10] * BCUR[2][2], w2_); \
        const float s3 = __builtin_amdgcn_fmed3f(ap[3] + BCUR[0][3], ap[11] * BCUR[2][3], w3); \
        const float s4 = __builtin_amdgcn_fmed3f(ap[4] + BCUR[1][0], ap[12] * BCUR[3][0], w4); \
        const float s5 = __builtin_amdgcn_fmed3f(ap[5] + BCUR[1][1], ap[13] * BCUR[3][1], w5); \
        const float s6 = __builtin_amdgcn_fmed3f(ap[6] + BCUR[1][2], ap[14] * BCUR[3][2], w6); \
        const float s7 = __builtin_amdgcn_fmed3f(ap[7] + BCUR[1][3], ap[15] * BCUR[3][3], w7); \
        acc[r] += ((s0 + s1) + (s2 + s3)) + ((s4 + s5) + (s6 + s7));           \
    } }

    LOADB(bA, 0)
#pragma unroll 1
    for (int ch = 0; ch < 16; ch += 2) {
        CHUNK(ch,     bA, bB)
        CHUNK(ch + 1, bB, bA)
    }
#undef CHUNK
#undef LOADB

    // --- epilogue: per-row inverse-distance, reduce over 64 m-lanes -------------
    const float w2sum = *w2sum_p;
    const float rv    = brew[m0 + lane];

#pragma unroll
    for (int r = 0; r < 8; ++r) {
        const float dist = fabsf(acc[r] - w2sum);
        const float wgt  = 1.0f / (dist + 1e-4f);
        float sw  = wgt;
        float swr = wgt * rv;
#pragma unroll
        for (int k = 1; k < 64; k <<= 1) {
            sw  += __shfl_xor(sw, k);
            swr += __shfl_xor(swr, k);
        }
        if (lane == 0) {
            const int n = n0 + r;
            partials[((size_t)n * MT + mt) * 2 + 0] = sw;
            partials[((size_t)n * MT + mt) * 2 + 1] = swr;
        }
    }
}

// --- Kernel 3: reduce tile partials, divide ------------------------------------
__global__ __launch_bounds__(256) void finalize_kernel(
    const float* __restrict__ partials, float* __restrict__ out)
{
    const int n = blockIdx.x * 256 + threadIdx.x;
    if (n < NROWS) {
        float sw = 0.0f, swr = 0.0f;
#pragma unroll
        for (int t = 0; t < MT; ++t) {
            sw  += partials[((size_t)n * MT + t) * 2 + 0];
            swr += partials[((size_t)n * MT + t) * 2 + 1];
        }
        out[n] = swr / sw;
    }
}

extern "C" void kernel_launch(void* const* d_in, const int* in_sizes, int n_in,
                              void* d_out, int out_size, void* d_ws, size_t ws_size,
                              hipStream_t stream)
{
    const float* embeds       = (const float*)d_in[0];  // [2048,128]
    const float* base_embeds  = (const float*)d_in[1];  // [2048,128]
    const float* base_rewards = (const float*)d_in[2];  // [2048]
    const float* W1           = (const float*)d_in[3];  // [128,128] (in,out)
    const float* w2           = (const float*)d_in[4];  // [128,1]
    float* out = (float*)d_out;

    // ws: partials [2048*MT*2] | PA [2048*256] | BT4 [64*2048*4] | w2sum[1]
    float* partials = (float*)d_ws;
    float* PA  = partials + (size_t)NROWS * MT * 2;
    float* BT4 = PA + (size_t)NROWS * 256;
    float* w2s = BT4 + (size_t)64 * 2048 * 4;

    proj_kernel<<<(NROWS + MROWS) / 2, 256, 0, stream>>>(
        embeds, base_embeds, W1, w2, PA, BT4, w2s);

    dim3 grid2(NROWS / 32, MROWS / 64);
    pair_kernel<<<grid2, 256, 0, stream>>>(PA, BT4, w2, w2s, base_rewards, partials);

    finalize_kernel<<<(NROWS + 255) / 256, 256, 0, stream>>>(partials, out);
}